// Round 14
// baseline (52.325 us; speedup 1.0000x reference)
//
#include <hip/hip_runtime.h>

typedef float f4 __attribute__((ext_vector_type(4)));
typedef float f4u __attribute__((ext_vector_type(4), aligned(4)));

struct M3 { float m[3][3]; };

#define ELEM(q, n) ((q)[(n) >> 2][(n) & 3])

__device__ __forceinline__ M3 matmul(const M3& A, const M3& B) {  // A @ B
  M3 C;
#pragma unroll
  for (int i = 0; i < 3; ++i)
#pragma unroll
    for (int j = 0; j < 3; ++j)
      C.m[i][j] = A.m[i][0]*B.m[0][j] + A.m[i][1]*B.m[1][j] + A.m[i][2]*B.m[2][j];
  return C;
}

__device__ __forceinline__ M3 mk18(const f4 (&q)[18], int k) {
  M3 A;
#pragma unroll
  for (int i = 0; i < 3; ++i)
#pragma unroll
    for (int j = 0; j < 3; ++j)
      A.m[i][j] = ELEM(q, 9*k + 3*i + j);
  return A;
}

template <int CTRL>
__device__ __forceinline__ float dppf(float v) {
  return __int_as_float(
      __builtin_amdgcn_mov_dpp(__float_as_int(v), CTRL, 0xf, 0xf, true));
}

template <int D>  // row_shr:D (8-lane subgroups are 8-aligned; masked by s>=D)
__device__ __forceinline__ M3 dpp_shr_mat(const M3& A) {
  M3 C;
#pragma unroll
  for (int i = 0; i < 3; ++i)
#pragma unroll
    for (int j = 0; j < 3; ++j)
      C.m[i][j] = dppf<0x110 + D>(A.m[i][j]);
  return C;
}

__device__ __forceinline__ float sigm(float z) {
  return __builtin_amdgcn_rcpf(1.0f + __expf(-z));
}
__device__ __forceinline__ float tanh_(float z) {
  float e = __expf(2.0f * z);
  return 1.0f - 2.0f * __builtin_amdgcn_rcpf(e + 1.0f);
}

template <int CTRL>
__device__ __forceinline__ float quad_bcast(float v) {
  return __int_as_float(
      __builtin_amdgcn_mov_dpp(__float_as_int(v), CTRL, 0xf, 0xf, true));
}

// One wave per block, 16 elements, 4 iterations (g0-back, g0-fwd, g1-back,
// g1-fwd). R data is staged global->LDS ASYNCHRONOUSLY (global_load_lds,
// zero VGPR cost -> compiler cannot sink it) with double buffering and
// counted vmcnt waits: iteration k+1's 18 KB is in flight during the whole
// compute of iteration k. Single-wave block: no barriers needed.
__global__ __launch_bounds__(64) void fused_kernel(
    const float* __restrict__ dir, const float* __restrict__ R,
    const float* __restrict__ Wih, const float* __restrict__ Whh,
    const float* __restrict__ bih, const float* __restrict__ bhh,
    float* __restrict__ out, int B) {
  __shared__ __align__(16) f4 stage[2][18 * 64];  // 2 x 18 KB staging
  __shared__ __align__(16) f4 xrows[64 * 16];     // 16 KB LSTM x rows

  const int lane = threadIdx.x;
  const int e8 = lane >> 3;   // element within group (0..7)
  const int s = lane & 7;     // segment within chain
  const int b0 = blockIdx.x * 16;

  // per-lane global source address for iteration it (0..3)
  auto gsrc = [&](int it) -> const f4* {
    const int g = it >> 1, phase = it & 1;
    int bb = b0 + g * 8 + e8; bb = (bb < B) ? bb : (B - 1);
    const f4* Rb4 = (const f4*)(R + (size_t)bb * 1152);
    return (phase == 0) ? (Rb4 + 18 * (7 - s)) : (Rb4 + 144 + 18 * s);
  };

  // stage iteration it's 18 KB into buffer buf: instruction i deposits
  // lane L's chunk at stage[buf][i*64 + L] (HW: uniform base + lane*16)
  auto do_stage = [&](int it, int buf) {
    const f4* p = gsrc(it);
#pragma unroll
    for (int i = 0; i < 18; ++i)
      __builtin_amdgcn_global_load_lds(p + i, &stage[buf][i * 64], 16, 0, 0);
  };

  do_stage(0, 0);  // prologue

#pragma unroll 1
  for (int it = 0; it < 4; ++it) {
    const int g = it >> 1;
    const int phase = it & 1;           // 0 = back, 1 = fwd (wave-uniform)
    const int buf = it & 1;
    const int b = b0 + g * 8 + e8;
    const bool valid = (b < B);
    const int bc = valid ? b : (B - 1);

    if (it < 3) do_stage(it + 1, buf ^ 1);

    // wait: >=18 in flight are the NEXT tile; everything older (this tile's
    // 18 + prior stores) has retired (vmcnt is FIFO). Last iter: drain all.
    if (it < 3) asm volatile("s_waitcnt vmcnt(18)" ::: "memory");
    else        asm volatile("s_waitcnt vmcnt(0)" ::: "memory");
    __builtin_amdgcn_sched_barrier(0);

    // bulk LDS -> regs: lane reads its own 18 chunks (conflict-free)
    f4 q[18];
    {
      const f4* sb = &stage[buf][lane];
#pragma unroll
      for (int i = 0; i < 18; ++i) q[i] = sb[i * 64];
    }

    const float d0 = dir[3*bc+0], d1 = dir[3*bc+1], d2 = dir[3*bc+2];

    // ---- segment product P = A7 @ ... @ A0 ----
    M3 P = mk18(q, 0);
#pragma unroll
    for (int k = 1; k < 8; ++k) P = matmul(mk18(q, k), P);

    // ---- 8-lane DPP scan; combine order by phase (uniform) ----
    M3 I = P;
    {
      M3 Sh = dpp_shr_mat<1>(I);
      M3 T; if (phase == 0) T = matmul(Sh, I); else T = matmul(I, Sh);
#pragma unroll
      for (int i = 0; i < 3; ++i)
#pragma unroll
        for (int j = 0; j < 3; ++j) I.m[i][j] = (s >= 1) ? T.m[i][j] : I.m[i][j];
    }
    {
      M3 Sh = dpp_shr_mat<2>(I);
      M3 T; if (phase == 0) T = matmul(Sh, I); else T = matmul(I, Sh);
#pragma unroll
      for (int i = 0; i < 3; ++i)
#pragma unroll
        for (int j = 0; j < 3; ++j) I.m[i][j] = (s >= 2) ? T.m[i][j] : I.m[i][j];
    }
    {
      M3 Sh = dpp_shr_mat<4>(I);
      M3 T; if (phase == 0) T = matmul(Sh, I); else T = matmul(I, Sh);
#pragma unroll
      for (int i = 0; i < 3; ++i)
#pragma unroll
        for (int j = 0; j < 3; ++j) I.m[i][j] = (s >= 4) ? T.m[i][j] : I.m[i][j];
    }

    if (phase == 0) {
      // ======== BACK: w = I^T d; rows r <- r^T A; rows 8s..8s+7 ========
      float w0 = I.m[0][0]*d0 + I.m[1][0]*d1 + I.m[2][0]*d2;
      float w1 = I.m[0][1]*d0 + I.m[1][1]*d1 + I.m[2][1]*d2;
      float w2 = I.m[0][2]*d0 + I.m[1][2]*d1 + I.m[2][2]*d2;
      float p0 = dppf<0x111>(w0), p1 = dppf<0x111>(w1), p2 = dppf<0x111>(w2);
      float v0 = (s == 0) ? d0 : p0;
      float v1 = (s == 0) ? d1 : p1;
      float v2 = (s == 0) ? d2 : p2;

      float row[24];
#pragma unroll
      for (int j = 0; j < 8; ++j) {
        M3 A = mk18(q, 7 - j);
        float n0 = v0*A.m[0][0] + v1*A.m[1][0] + v2*A.m[2][0];
        float n1 = v0*A.m[0][1] + v1*A.m[1][1] + v2*A.m[2][1];
        float n2 = v0*A.m[0][2] + v1*A.m[1][2] + v2*A.m[2][2];
        v0 = n0; v1 = n1; v2 = n2;
        row[3*j+0] = n0; row[3*j+1] = n1; row[3*j+2] = n2;
      }

      if (valid) {
        float* ob = out + (size_t)b * 384 + 24 * s;
#pragma unroll
        for (int kk = 0; kk < 6; ++kk) {
          f4 vv = { row[4*kk+0], row[4*kk+1], row[4*kk+2], row[4*kk+3] };
          ((f4*)ob)[kk] = vv;
        }
      }
#pragma unroll
      for (int j = 0; j < 8; ++j) {
        f4 vv = { row[3*j+0], row[3*j+1], row[3*j+2], 0.f };
        xrows[(8*s + j) * 16 + g * 8 + e8] = vv;
      }
    } else {
      // ======== FWD: w = I d; rows r <- A r; rows 65+8s.. ========
      float w0 = I.m[0][0]*d0 + I.m[0][1]*d1 + I.m[0][2]*d2;
      float w1 = I.m[1][0]*d0 + I.m[1][1]*d1 + I.m[1][2]*d2;
      float w2 = I.m[2][0]*d0 + I.m[2][1]*d1 + I.m[2][2]*d2;
      float p0 = dppf<0x111>(w0), p1 = dppf<0x111>(w1), p2 = dppf<0x111>(w2);
      float v0 = (s == 0) ? d0 : p0;
      float v1 = (s == 0) ? d1 : p1;
      float v2 = (s == 0) ? d2 : p2;

      float row[24];
#pragma unroll
      for (int j = 0; j < 8; ++j) {
        M3 A = mk18(q, j);
        float n0 = A.m[0][0]*v0 + A.m[0][1]*v1 + A.m[0][2]*v2;
        float n1 = A.m[1][0]*v0 + A.m[1][1]*v1 + A.m[1][2]*v2;
        float n2 = A.m[2][0]*v0 + A.m[2][1]*v1 + A.m[2][2]*v2;
        v0 = n0; v1 = n1; v2 = n2;
        row[3*j+0] = n0; row[3*j+1] = n1; row[3*j+2] = n2;
      }

      if (valid) {
        float* ob = out + (size_t)b * 384 + (size_t)(65 + 8*s) * 3;
#pragma unroll
        for (int kk = 0; kk < 5; ++kk) {
          f4u vv = { row[4*kk+0], row[4*kk+1], row[4*kk+2], row[4*kk+3] };
          *(f4u*)(ob + 4*kk) = vv;
        }
        ob[20] = row[20];
        if (s < 7) { ob[21] = row[21]; ob[22] = row[22]; ob[23] = row[23]; }
      }
    }
  }

  // ============ LSTM: 16 elements x 4 lanes = full wave ============
  const int e2 = lane >> 2;            // element 0..15
  const int u = lane & 3, uu = (u == 3) ? 0 : u;
  const int b2 = b0 + e2;
  const bool valid2 = (b2 < B);
  const int b2c = valid2 ? b2 : 0;

  const float wii0 = Wih[uu*3+0],     wii1 = Wih[uu*3+1],     wii2 = Wih[uu*3+2];
  const float wif0 = Wih[(3+uu)*3+0], wif1 = Wih[(3+uu)*3+1], wif2 = Wih[(3+uu)*3+2];
  const float wig0 = Wih[(6+uu)*3+0], wig1 = Wih[(6+uu)*3+1], wig2 = Wih[(6+uu)*3+2];
  const float wio0 = Wih[(9+uu)*3+0], wio1 = Wih[(9+uu)*3+1], wio2 = Wih[(9+uu)*3+2];
  const float whi0 = Whh[uu*3+0],     whi1 = Whh[uu*3+1],     whi2 = Whh[uu*3+2];
  const float whf0 = Whh[(3+uu)*3+0], whf1 = Whh[(3+uu)*3+1], whf2 = Whh[(3+uu)*3+2];
  const float whg0 = Whh[(6+uu)*3+0], whg1 = Whh[(6+uu)*3+1], whg2 = Whh[(6+uu)*3+2];
  const float who0 = Whh[(9+uu)*3+0], who1 = Whh[(9+uu)*3+1], who2 = Whh[(9+uu)*3+2];
  const float bsi = bih[uu]   + bhh[uu];
  const float bsf = bih[3+uu] + bhh[3+uu];
  const float bsg = bih[6+uu] + bhh[6+uu];
  const float bso = bih[9+uu] + bhh[9+uu];
  const float dd0 = dir[3*b2c+0], dd1 = dir[3*b2c+1], dd2 = dir[3*b2c+2];

  float h0 = 0.f, h1 = 0.f, h2 = 0.f, cc = 0.f, hl = 0.f;

#define LSTEP(x0_, x1_, x2_)                                                  \
  {                                                                           \
    float zi = bsi + wii0*(x0_) + wii1*(x1_) + wii2*(x2_)                     \
                   + whi0*h0 + whi1*h1 + whi2*h2;                             \
    float zf = bsf + wif0*(x0_) + wif1*(x1_) + wif2*(x2_)                     \
                   + whf0*h0 + whf1*h1 + whf2*h2;                             \
    float zg = bsg + wig0*(x0_) + wig1*(x1_) + wig2*(x2_)                     \
                   + whg0*h0 + whg1*h1 + whg2*h2;                             \
    float zo = bso + wio0*(x0_) + wio1*(x1_) + wio2*(x2_)                     \
                   + who0*h0 + who1*h1 + who2*h2;                             \
    float ai = sigm(zi), af = sigm(zf), ag = tanh_(zg), ao = sigm(zo);        \
    cc = af*cc + ai*ag;                                                       \
    float hn = ao * tanh_(cc);                                                \
    hl = hn;                                                                  \
    h0 = quad_bcast<0x00>(hn);                                                \
    h1 = quad_bcast<0x55>(hn);                                                \
    h2 = quad_bcast<0xAA>(hn);                                                \
  }

#pragma unroll 1
  for (int c = 0; c < 8; ++c) {
    f4 xa[8];
#pragma unroll
    for (int j = 0; j < 8; ++j) xa[j] = xrows[(c * 8 + j) * 16 + e2];
#pragma unroll
    for (int j = 0; j < 8; ++j) LSTEP(xa[j][0], xa[j][1], xa[j][2]);
  }
  LSTEP(dd0, dd1, dd2);  // final step t=64 with x = dir
#undef LSTEP

  if (valid2 && u < 3) out[(size_t)b2 * 384 + 192 + u] = hl;
}

extern "C" void kernel_launch(void* const* d_in, const int* in_sizes, int n_in,
                              void* d_out, int out_size, void* d_ws, size_t ws_size,
                              hipStream_t stream) {
  const float* dir = (const float*)d_in[0];
  const float* R   = (const float*)d_in[1];
  const float* Wih = (const float*)d_in[2];
  const float* Whh = (const float*)d_in[3];
  const float* bih = (const float*)d_in[4];
  const float* bhh = (const float*)d_in[5];
  float* out = (float*)d_out;

  const int B = in_sizes[0] / 3;   // 16384
  const int grid = (B + 15) / 16;  // 1024 one-wave blocks
  hipLaunchKernelGGL(fused_kernel, dim3(grid), dim3(64), 0, stream,
                     dir, R, Wih, Whh, bih, bhh, out, B);
}

// Round 15
// 47.310 us; speedup vs baseline: 1.1060x; 1.1060x over previous
//
#include <hip/hip_runtime.h>

typedef float f4 __attribute__((ext_vector_type(4)));
typedef float f4u __attribute__((ext_vector_type(4), aligned(4)));

struct M3 { float m[3][3]; };

#define ELEM(q, n) ((q)[(n) >> 2][(n) & 3])

__device__ __forceinline__ M3 matmul(const M3& A, const M3& B) {  // A @ B
  M3 C;
#pragma unroll
  for (int i = 0; i < 3; ++i)
#pragma unroll
    for (int j = 0; j < 3; ++j)
      C.m[i][j] = A.m[i][0]*B.m[0][j] + A.m[i][1]*B.m[1][j] + A.m[i][2]*B.m[2][j];
  return C;
}

__device__ __forceinline__ M3 mk18(const f4 (&q)[18], int k) {
  M3 A;
#pragma unroll
  for (int i = 0; i < 3; ++i)
#pragma unroll
    for (int j = 0; j < 3; ++j)
      A.m[i][j] = ELEM(q, 9*k + 3*i + j);
  return A;
}

template <int CTRL>
__device__ __forceinline__ float dppf(float v) {
  return __int_as_float(
      __builtin_amdgcn_mov_dpp(__float_as_int(v), CTRL, 0xf, 0xf, true));
}

template <int D>  // row_shr:D (8-lane subgroups are 8-aligned; masked by s>=D)
__device__ __forceinline__ M3 dpp_shr_mat(const M3& A) {
  M3 C;
#pragma unroll
  for (int i = 0; i < 3; ++i)
#pragma unroll
    for (int j = 0; j < 3; ++j)
      C.m[i][j] = dppf<0x110 + D>(A.m[i][j]);
  return C;
}

__device__ __forceinline__ float sigm(float z) {
  return __builtin_amdgcn_rcpf(1.0f + __expf(-z));
}
__device__ __forceinline__ float tanh_(float z) {
  float e = __expf(2.0f * z);
  return 1.0f - 2.0f * __builtin_amdgcn_rcpf(e + 1.0f);
}

template <int CTRL>
__device__ __forceinline__ float quad_bcast(float v) {
  return __int_as_float(
      __builtin_amdgcn_mov_dpp(__float_as_int(v), CTRL, 0xf, 0xf, true));
}

// Single shared blob so `stage` sits at LDS offset 0 (integer ds_read addressing).
struct SharedMem {
  f4 stage[2][18 * 64];  // 2 x 18 KB staging (offset 0 / 18432)
  f4 xrows[64 * 16];     // 16 KB LSTM x rows (offset 36864)
};

// One wave per block, 16 elements, 4 iterations (g0-back, g0-fwd, g1-back,
// g1-fwd). R staged global->LDS via global_load_lds (all 18 in flight, zero
// VGPR cost), double buffered, with FIFO-exact counted vmcnt waits so the
// next tile's loads stay in flight across the whole compute. ds_read of the
// staged tile is inline asm (integer LDS offsets) so the compiler cannot
// insert a conservative vmcnt(0). Single-wave block: no barriers.
__global__ __launch_bounds__(64) void fused_kernel(
    const float* __restrict__ dir, const float* __restrict__ R,
    const float* __restrict__ Wih, const float* __restrict__ Whh,
    const float* __restrict__ bih, const float* __restrict__ bhh,
    float* __restrict__ out, int B) {
  __shared__ __align__(16) SharedMem sm;

  const int lane = threadIdx.x;
  const int e8 = lane >> 3;   // element within group (0..7)
  const int s = lane & 7;     // segment within chain
  const int b0 = blockIdx.x * 16;

  auto gsrc = [&](int it) -> const f4* {
    const int g = it >> 1, phase = it & 1;
    int bb = b0 + g * 8 + e8; bb = (bb < B) ? bb : (B - 1);
    const f4* Rb4 = (const f4*)(R + (size_t)bb * 1152);
    return (phase == 0) ? (Rb4 + 18 * (7 - s)) : (Rb4 + 144 + 18 * s);
  };
  auto do_stage = [&](int it, int buf) {
    const f4* p = gsrc(it);
#pragma unroll
    for (int i = 0; i < 18; ++i)
      __builtin_amdgcn_global_load_lds(p + i, &sm.stage[buf][i * 64], 16, 0, 0);
  };

  do_stage(0, 0);  // prologue: tile 0 in flight

  // hoist + pin dir loads (keeps the vmcnt FIFO arithmetic exact)
  int bg0 = b0 + e8;            bg0 = (bg0 < B) ? bg0 : (B - 1);
  int bg1 = b0 + 8 + e8;        bg1 = (bg1 < B) ? bg1 : (B - 1);
  const float dA0 = dir[3*bg0+0], dA1 = dir[3*bg0+1], dA2 = dir[3*bg0+2];
  const float dB0 = dir[3*bg1+0], dB1 = dir[3*bg1+1], dB2 = dir[3*bg1+2];
  asm volatile("" :: "v"(dA0), "v"(dA1), "v"(dA2), "v"(dB0), "v"(dB1), "v"(dB2));

#pragma unroll 1
  for (int it = 0; it < 4; ++it) {
    const int g = it >> 1;
    const int phase = it & 1;           // 0 = back, 1 = fwd (wave-uniform)
    const int buf = it & 1;
    const int b = b0 + g * 8 + e8;
    const bool valid = (b < B);

    if (it < 3) do_stage(it + 1, buf ^ 1);

    // FIFO-exact counted waits (stores counted; never drains the next tile):
    // it0: [stage0(18), dir(6), stage1(18)] -> need 24 retired -> vmcnt(18)
    // it1/2: [stageK(18), stores(<=9), stageK+1(18)] -> vmcnt(24)
    // it3: [stage3(18), stores(6)] -> vmcnt(6)
    if (it == 0)      asm volatile("s_waitcnt vmcnt(18)" ::: "memory");
    else if (it < 3)  asm volatile("s_waitcnt vmcnt(24)" ::: "memory");
    else              asm volatile("s_waitcnt vmcnt(6)"  ::: "memory");
    __builtin_amdgcn_sched_barrier(0);

    // asm ds_read: lane's 18 chunks at stage[buf] + lane*16, stride 1 KB
    f4 q[18];
    {
      unsigned base = (unsigned)(buf * 18432 + lane * 16);
#define DSR(i, off) \
      asm volatile("ds_read_b128 %0, %1 offset:" #off : "=v"(q[i]) : "v"(base))
      DSR(0, 0);      DSR(1, 1024);   DSR(2, 2048);   DSR(3, 3072);
      DSR(4, 4096);   DSR(5, 5120);   DSR(6, 6144);   DSR(7, 7168);
      DSR(8, 8192);   DSR(9, 9216);   DSR(10, 10240); DSR(11, 11264);
      DSR(12, 12288); DSR(13, 13312); DSR(14, 14336); DSR(15, 15360);
      DSR(16, 16384); DSR(17, 17408);
#undef DSR
      asm volatile("s_waitcnt lgkmcnt(0)" ::: "memory");
      __builtin_amdgcn_sched_barrier(0);
    }

    const float d0 = (g == 0) ? dA0 : dB0;
    const float d1 = (g == 0) ? dA1 : dB1;
    const float d2 = (g == 0) ? dA2 : dB2;

    // ---- segment product P = A7 @ ... @ A0 ----
    M3 P = mk18(q, 0);
#pragma unroll
    for (int k = 1; k < 8; ++k) P = matmul(mk18(q, k), P);

    // ---- 8-lane DPP scan; combine order by phase (uniform) ----
    M3 I = P;
    {
      M3 Sh = dpp_shr_mat<1>(I);
      M3 T; if (phase == 0) T = matmul(Sh, I); else T = matmul(I, Sh);
#pragma unroll
      for (int i = 0; i < 3; ++i)
#pragma unroll
        for (int j = 0; j < 3; ++j) I.m[i][j] = (s >= 1) ? T.m[i][j] : I.m[i][j];
    }
    {
      M3 Sh = dpp_shr_mat<2>(I);
      M3 T; if (phase == 0) T = matmul(Sh, I); else T = matmul(I, Sh);
#pragma unroll
      for (int i = 0; i < 3; ++i)
#pragma unroll
        for (int j = 0; j < 3; ++j) I.m[i][j] = (s >= 2) ? T.m[i][j] : I.m[i][j];
    }
    {
      M3 Sh = dpp_shr_mat<4>(I);
      M3 T; if (phase == 0) T = matmul(Sh, I); else T = matmul(I, Sh);
#pragma unroll
      for (int i = 0; i < 3; ++i)
#pragma unroll
        for (int j = 0; j < 3; ++j) I.m[i][j] = (s >= 4) ? T.m[i][j] : I.m[i][j];
    }

    if (phase == 0) {
      // ======== BACK: w = I^T d; rows r <- r^T A; rows 8s..8s+7 ========
      float w0 = I.m[0][0]*d0 + I.m[1][0]*d1 + I.m[2][0]*d2;
      float w1 = I.m[0][1]*d0 + I.m[1][1]*d1 + I.m[2][1]*d2;
      float w2 = I.m[0][2]*d0 + I.m[1][2]*d1 + I.m[2][2]*d2;
      float p0 = dppf<0x111>(w0), p1 = dppf<0x111>(w1), p2 = dppf<0x111>(w2);
      float v0 = (s == 0) ? d0 : p0;
      float v1 = (s == 0) ? d1 : p1;
      float v2 = (s == 0) ? d2 : p2;

      float row[24];
#pragma unroll
      for (int j = 0; j < 8; ++j) {
        M3 A = mk18(q, 7 - j);
        float n0 = v0*A.m[0][0] + v1*A.m[1][0] + v2*A.m[2][0];
        float n1 = v0*A.m[0][1] + v1*A.m[1][1] + v2*A.m[2][1];
        float n2 = v0*A.m[0][2] + v1*A.m[1][2] + v2*A.m[2][2];
        v0 = n0; v1 = n1; v2 = n2;
        row[3*j+0] = n0; row[3*j+1] = n1; row[3*j+2] = n2;
      }

      if (valid) {
        float* ob = out + (size_t)b * 384 + 24 * s;
#pragma unroll
        for (int kk = 0; kk < 6; ++kk) {
          f4 vv = { row[4*kk+0], row[4*kk+1], row[4*kk+2], row[4*kk+3] };
          ((f4*)ob)[kk] = vv;
        }
      }
#pragma unroll
      for (int j = 0; j < 8; ++j) {
        f4 vv = { row[3*j+0], row[3*j+1], row[3*j+2], 0.f };
        sm.xrows[(8*s + j) * 16 + g * 8 + e8] = vv;
      }
    } else {
      // ======== FWD: w = I d; rows r <- A r; rows 65+8s.. ========
      float w0 = I.m[0][0]*d0 + I.m[0][1]*d1 + I.m[0][2]*d2;
      float w1 = I.m[1][0]*d0 + I.m[1][1]*d1 + I.m[1][2]*d2;
      float w2 = I.m[2][0]*d0 + I.m[2][1]*d1 + I.m[2][2]*d2;
      float p0 = dppf<0x111>(w0), p1 = dppf<0x111>(w1), p2 = dppf<0x111>(w2);
      float v0 = (s == 0) ? d0 : p0;
      float v1 = (s == 0) ? d1 : p1;
      float v2 = (s == 0) ? d2 : p2;

      float row[24];
#pragma unroll
      for (int j = 0; j < 8; ++j) {
        M3 A = mk18(q, j);
        float n0 = A.m[0][0]*v0 + A.m[0][1]*v1 + A.m[0][2]*v2;
        float n1 = A.m[1][0]*v0 + A.m[1][1]*v1 + A.m[1][2]*v2;
        float n2 = A.m[2][0]*v0 + A.m[2][1]*v1 + A.m[2][2]*v2;
        v0 = n0; v1 = n1; v2 = n2;
        row[3*j+0] = n0; row[3*j+1] = n1; row[3*j+2] = n2;
      }

      if (valid) {
        float* ob = out + (size_t)b * 384 + (size_t)(65 + 8*s) * 3;
#pragma unroll
        for (int kk = 0; kk < 5; ++kk) {
          f4u vv = { row[4*kk+0], row[4*kk+1], row[4*kk+2], row[4*kk+3] };
          *(f4u*)(ob + 4*kk) = vv;
        }
        ob[20] = row[20];
        if (s < 7) { ob[21] = row[21]; ob[22] = row[22]; ob[23] = row[23]; }
      }
    }
  }

  // ============ LSTM: 16 elements x 4 lanes = full wave ============
  const int e2 = lane >> 2;            // element 0..15
  const int u = lane & 3, uu = (u == 3) ? 0 : u;
  const int b2 = b0 + e2;
  const bool valid2 = (b2 < B);
  const int b2c = valid2 ? b2 : 0;

  const float wii0 = Wih[uu*3+0],     wii1 = Wih[uu*3+1],     wii2 = Wih[uu*3+2];
  const float wif0 = Wih[(3+uu)*3+0], wif1 = Wih[(3+uu)*3+1], wif2 = Wih[(3+uu)*3+2];
  const float wig0 = Wih[(6+uu)*3+0], wig1 = Wih[(6+uu)*3+1], wig2 = Wih[(6+uu)*3+2];
  const float wio0 = Wih[(9+uu)*3+0], wio1 = Wih[(9+uu)*3+1], wio2 = Wih[(9+uu)*3+2];
  const float whi0 = Whh[uu*3+0],     whi1 = Whh[uu*3+1],     whi2 = Whh[uu*3+2];
  const float whf0 = Whh[(3+uu)*3+0], whf1 = Whh[(3+uu)*3+1], whf2 = Whh[(3+uu)*3+2];
  const float whg0 = Whh[(6+uu)*3+0], whg1 = Whh[(6+uu)*3+1], whg2 = Whh[(6+uu)*3+2];
  const float who0 = Whh[(9+uu)*3+0], who1 = Whh[(9+uu)*3+1], who2 = Whh[(9+uu)*3+2];
  const float bsi = bih[uu]   + bhh[uu];
  const float bsf = bih[3+uu] + bhh[3+uu];
  const float bsg = bih[6+uu] + bhh[6+uu];
  const float bso = bih[9+uu] + bhh[9+uu];
  const float dd0 = dir[3*b2c+0], dd1 = dir[3*b2c+1], dd2 = dir[3*b2c+2];

  float h0 = 0.f, h1 = 0.f, h2 = 0.f, cc = 0.f, hl = 0.f;

#define LSTEP(x0_, x1_, x2_)                                                  \
  {                                                                           \
    float zi = bsi + wii0*(x0_) + wii1*(x1_) + wii2*(x2_)                     \
                   + whi0*h0 + whi1*h1 + whi2*h2;                             \
    float zf = bsf + wif0*(x0_) + wif1*(x1_) + wif2*(x2_)                     \
                   + whf0*h0 + whf1*h1 + whf2*h2;                             \
    float zg = bsg + wig0*(x0_) + wig1*(x1_) + wig2*(x2_)                     \
                   + whg0*h0 + whg1*h1 + whg2*h2;                             \
    float zo = bso + wio0*(x0_) + wio1*(x1_) + wio2*(x2_)                     \
                   + who0*h0 + who1*h1 + who2*h2;                             \
    float ai = sigm(zi), af = sigm(zf), ag = tanh_(zg), ao = sigm(zo);        \
    cc = af*cc + ai*ag;                                                       \
    float hn = ao * tanh_(cc);                                                \
    hl = hn;                                                                  \
    h0 = quad_bcast<0x00>(hn);                                                \
    h1 = quad_bcast<0x55>(hn);                                                \
    h2 = quad_bcast<0xAA>(hn);                                                \
  }

#pragma unroll 1
  for (int c = 0; c < 8; ++c) {
    f4 xa[8];
#pragma unroll
    for (int j = 0; j < 8; ++j) xa[j] = sm.xrows[(c * 8 + j) * 16 + e2];
#pragma unroll
    for (int j = 0; j < 8; ++j) LSTEP(xa[j][0], xa[j][1], xa[j][2]);
  }
  LSTEP(dd0, dd1, dd2);  // final step t=64 with x = dir
#undef LSTEP

  if (valid2 && u < 3) out[(size_t)b2 * 384 + 192 + u] = hl;
}

extern "C" void kernel_launch(void* const* d_in, const int* in_sizes, int n_in,
                              void* d_out, int out_size, void* d_ws, size_t ws_size,
                              hipStream_t stream) {
  const float* dir = (const float*)d_in[0];
  const float* R   = (const float*)d_in[1];
  const float* Wih = (const float*)d_in[2];
  const float* Whh = (const float*)d_in[3];
  const float* bih = (const float*)d_in[4];
  const float* bhh = (const float*)d_in[5];
  float* out = (float*)d_out;

  const int B = in_sizes[0] / 3;   // 16384
  const int grid = (B + 15) / 16;  // 1024 one-wave blocks
  hipLaunchKernelGGL(fused_kernel, dim3(grid), dim3(64), 0, stream,
                     dir, R, Wih, Whh, bih, bhh, out, B);
}